// Round 1
// baseline (718.933 us; speedup 1.0000x reference)
//
#include <hip/hip_runtime.h>

// Problem constants
#define NBATCH 16
#define CIN 16
#define COUT 32
#define DIN 16
#define HIN 32
#define WIN 32
#define DOUT 31
#define HOUT 63
#define WOUT 63
#define S_SPATIAL (DOUT*HOUT*WOUT)          // 123039
#define TOTAL_OUT (NBATCH*COUT*S_SPATIAL)   // 62995968

// ws layout (floats): [0,512) sp_sum[n*32+c], [512,544) ch_sumsq[c],
//                     [544,576) scale[c],     [576,1088) m[n*32+c]
#define WS_SPSUM 0
#define WS_CHSQ 512
#define WS_SCALE 544
#define WS_M 576

__global__ __launch_bounds__(256) void convt_kernel(
    const float* __restrict__ x, const float* __restrict__ w,
    float* __restrict__ out, float* __restrict__ ws)
{
    const int od  = blockIdx.x >> 2;
    const int ohg = blockIdx.x & 3;
    const int co  = blockIdx.y;
    const int n   = blockIdx.z;
    const int tx  = threadIdx.x & 31;
    const int ty  = threadIdx.x >> 5;

    // Stage this co's weights: wl[ci][kd][kh*3+kw]
    __shared__ float wl[CIN][3][9];
    for (int t = threadIdx.x; t < CIN * 27; t += 256) {
        int ci = t / 27, k = t % 27;
        wl[ci][k / 9][k % 9] = w[(ci * COUT + co) * 27 + k];
    }
    __syncthreads();

    const int r   = (ohg << 3) + ty;   // oh-slot 0..31
    const int oh0 = r << 1;            // even oh
    const int c   = tx;                // iw base 0..31
    const int ow0 = c << 1;            // even ow
    const bool vh = (oh0 < HOUT - 1);  // oh0+1 exists
    const bool vw = (ow0 < WOUT - 1);  // ow0+1 exists
    const int r1  = vh ? r + 1 : r;
    const int c1  = vw ? c + 1 : c;

    // depth taps (block-uniform): even od -> {(od/2, kd=1)}; odd -> {((od+1)/2,0), ((od-1)/2,2)}
    int id0, kd0, id1 = 0, kd1 = 0, ndt;
    if ((od & 1) == 0) { id0 = od >> 1; kd0 = 1; ndt = 1; }
    else { id0 = (od + 1) >> 1; kd0 = 0; id1 = (od - 1) >> 1; kd1 = 2; ndt = 2; }

    float a00 = 0.f, a01 = 0.f, a10 = 0.f, a11 = 0.f;
    const float* xn = x + (size_t)n * CIN * DIN * HIN * WIN;
    for (int ci = 0; ci < CIN; ++ci) {
        const float* xc = xn + ci * DIN * HIN * WIN;
        for (int t = 0; t < ndt; ++t) {
            const int id = t ? id1 : id0;
            const int kd = t ? kd1 : kd0;
            const float* x0 = xc + id * HIN * WIN + r * WIN;
            const float* x1 = xc + id * HIN * WIN + r1 * WIN;
            const float x00 = x0[c], x01 = x0[c1];
            const float x10 = x1[c], x11 = x1[c1];
            const float* wp = wl[ci][kd];
            a00 = fmaf(x00, wp[4], a00);
            a01 = fmaf(x00, wp[5], fmaf(x01, wp[3], a01));
            a10 = fmaf(x10, wp[1], fmaf(x00, wp[7], a10));
            a11 = fmaf(x10, wp[2], fmaf(x11, wp[0],
                  fmaf(x00, wp[8], fmaf(x01, wp[6], a11))));
        }
    }

    // store + accumulate statistics over valid outputs
    const size_t ob = ((((size_t)n * COUT + co) * DOUT + od) * HOUT + oh0) * WOUT + ow0;
    out[ob] = a00;
    float s = a00, q = a00 * a00;
    if (vw) { out[ob + 1] = a01; s += a01; q = fmaf(a01, a01, q); }
    if (vh) {
        out[ob + WOUT] = a10; s += a10; q = fmaf(a10, a10, q);
        if (vw) { out[ob + WOUT + 1] = a11; s += a11; q = fmaf(a11, a11, q); }
    }

    // wave(64) reduce then cross-wave via LDS, then 2 atomics/block
    for (int off = 32; off > 0; off >>= 1) {
        s += __shfl_down(s, off);
        q += __shfl_down(q, off);
    }
    __shared__ float rs[4], rq[4];
    const int wid = threadIdx.x >> 6;
    const int lane = threadIdx.x & 63;
    if (lane == 0) { rs[wid] = s; rq[wid] = q; }
    __syncthreads();
    if (threadIdx.x == 0) {
        float S_ = rs[0] + rs[1] + rs[2] + rs[3];
        float Q_ = rq[0] + rq[1] + rq[2] + rq[3];
        atomicAdd(&ws[WS_SPSUM + n * COUT + co], S_);
        atomicAdd(&ws[WS_CHSQ + co], Q_);
    }
}

__global__ void stats_kernel(const float* __restrict__ bnw, float* __restrict__ ws)
{
    const int t = threadIdx.x;
    const float inv_s = 1.0f / (float)S_SPATIAL;
    if (t < 512) ws[WS_M + t] = ws[WS_SPSUM + t] * inv_s;  // per-(n,c) spatial mean
    if (t < COUT) {
        float sum = 0.f;
        for (int n2 = 0; n2 < NBATCH; ++n2) sum += ws[WS_SPSUM + n2 * COUT + t];
        const float cnt = (float)NBATCH * (float)S_SPATIAL;
        const float mean = sum / cnt;
        const float var = ws[WS_CHSQ + t] / cnt - mean * mean;
        ws[WS_SCALE + t] = bnw[t] * rsqrtf(var + 1e-5f);
    }
}

__global__ __launch_bounds__(256) void norm_kernel(float* __restrict__ out,
                                                   const float* __restrict__ ws)
{
    const float* __restrict__ m  = ws + WS_M;
    const float* __restrict__ sc = ws + WS_SCALE;
    constexpr int NV = TOTAL_OUT / 4;
    const int i = blockIdx.x * 256 + threadIdx.x;
    if (i >= NV) return;
    float4 v = reinterpret_cast<float4*>(out)[i];
    const int base = i * 4;
    const int nc0 = base / S_SPATIAL;          // compiler magic-div
    const int rem = base - nc0 * S_SPATIAL;
    float a[4] = { v.x, v.y, v.z, v.w };
#pragma unroll
    for (int j = 0; j < 4; ++j) {
        const int nc = nc0 + ((rem + j) >= S_SPATIAL ? 1 : 0);
        a[j] = (a[j] - m[nc]) * sc[nc & (COUT - 1)];
    }
    v.x = a[0]; v.y = a[1]; v.z = a[2]; v.w = a[3];
    reinterpret_cast<float4*>(out)[i] = v;
}

extern "C" void kernel_launch(void* const* d_in, const int* in_sizes, int n_in,
                              void* d_out, int out_size, void* d_ws, size_t ws_size,
                              hipStream_t stream)
{
    const float* x   = (const float*)d_in[0];
    const float* w   = (const float*)d_in[1];
    // d_in[2] = conv_bias, d_in[4] = bn_bias: both cancel algebraically.
    const float* bnw = (const float*)d_in[3];
    float* out = (float*)d_out;
    float* ws  = (float*)d_ws;

    hipMemsetAsync(ws, 0, 544 * sizeof(float), stream);

    dim3 grid(DOUT * 4, COUT, NBATCH);
    convt_kernel<<<grid, 256, 0, stream>>>(x, w, out, ws);

    stats_kernel<<<1, 512, 0, stream>>>(bnw, ws);

    const int nv = TOTAL_OUT / 4;
    norm_kernel<<<(nv + 255) / 256, 256, 0, stream>>>(out, ws);
}

// Round 4
// 495.645 us; speedup vs baseline: 1.4505x; 1.4505x over previous
//
#include <hip/hip_runtime.h>

// Problem constants
#define NBATCH 16
#define CIN 16
#define COUT 32
#define DIN 16
#define HIN 32
#define WIN 32
#define DOUT 31
#define HOUT 63
#define WOUT 63
#define S_SPATIAL (DOUT*HOUT*WOUT)          // 123039
#define CNT_ALL ((float)NBATCH*(float)S_SPATIAL)

// ws layout (float offsets)
// partial sums  ps[odrb(496)][n(16)][co(32)]  : 253952
// partial sumsq qs[...same...]                : 253952
// accS[512], accQ[512], m[512], scale[32]
#define WS_PS   0
#define WS_QS   253952
#define WS_ACCS 507904
#define WS_ACCQ 508416
#define WS_M    508928
#define WS_SC   509440

// Per block: (rb, od, n). 256 threads = 4 waves; wave w owns co-octet w.
// Lane: c = lane&31 (ow0=2c), rp = lane>>5, r = 2*rb+rp (oh0=2r).
// Thread computes 2x2 spatial x 8 co = 32 accumulators.
template<int WRITE>
__global__ __launch_bounds__(256) void conv_pass(
    const float* __restrict__ x, const float* __restrict__ w,
    float* __restrict__ out, float* __restrict__ ws)
{
    const int rb = blockIdx.x;
    const int od = blockIdx.y;
    const int n  = blockIdx.z;
    const int tid  = threadIdx.x;
    const int cob  = __builtin_amdgcn_readfirstlane((tid >> 6) << 3); // 0,8,16,24
    const int lane = tid & 63;
    const int c  = lane & 31;
    const int rp = lane >> 5;
    const int r  = (rb << 1) + rp;
    const bool vh = (r < 31);
    const bool vw = (c < 31);
    const int c1 = vw ? c + 1 : c;
    const int r1 = vh ? r + 1 : r;

    // depth taps (block-uniform): even od -> {(od/2, kd=1)}; odd -> {((od+1)/2,0), ((od-1)/2,2)}
    int id0, kd0, id1 = 0, ndt;
    if ((od & 1) == 0) { id0 = od >> 1; kd0 = 1; ndt = 1; }
    else { id0 = (od + 1) >> 1; kd0 = 0; id1 = (od - 1) >> 1; ndt = 2; }

    float acc[8][4];
#pragma unroll
    for (int j = 0; j < 8; ++j) { acc[j][0]=0.f; acc[j][1]=0.f; acc[j][2]=0.f; acc[j][3]=0.f; }

    for (int ci = 0; ci < CIN; ++ci) {
        const size_t xb = (size_t)(n * CIN + ci) * DIN;
        {   // tap 0
            const float* xp = x + (xb + id0) * (HIN * WIN);
            const float x00 = xp[r * WIN + c],  x01 = xp[r * WIN + c1];
            const float x10 = xp[r1 * WIN + c], x11 = xp[r1 * WIN + c1];
            const float* wb = w + (ci * COUT + cob) * 27 + kd0 * 9;   // wave-uniform -> s_load
#pragma unroll
            for (int j = 0; j < 8; ++j) {
                const float* wp = wb + j * 27;
                acc[j][0] = fmaf(x00, wp[4], acc[j][0]);
                acc[j][1] = fmaf(x00, wp[5], fmaf(x01, wp[3], acc[j][1]));
                acc[j][2] = fmaf(x10, wp[1], fmaf(x00, wp[7], acc[j][2]));
                acc[j][3] = fmaf(x10, wp[2], fmaf(x11, wp[0],
                            fmaf(x00, wp[8], fmaf(x01, wp[6], acc[j][3]))));
            }
        }
        if (ndt == 2) {   // tap 1, kd=2
            const float* xp = x + (xb + id1) * (HIN * WIN);
            const float x00 = xp[r * WIN + c],  x01 = xp[r * WIN + c1];
            const float x10 = xp[r1 * WIN + c], x11 = xp[r1 * WIN + c1];
            const float* wb = w + (ci * COUT + cob) * 27 + 2 * 9;
#pragma unroll
            for (int j = 0; j < 8; ++j) {
                const float* wp = wb + j * 27;
                acc[j][0] = fmaf(x00, wp[4], acc[j][0]);
                acc[j][1] = fmaf(x00, wp[5], fmaf(x01, wp[3], acc[j][1]));
                acc[j][2] = fmaf(x10, wp[1], fmaf(x00, wp[7], acc[j][2]));
                acc[j][3] = fmaf(x10, wp[2], fmaf(x11, wp[0],
                            fmaf(x00, wp[8], fmaf(x01, wp[6], acc[j][3]))));
            }
        }
    }

    if (WRITE == 0) {
        // Per-co stats over valid outputs, wave-level butterfly reduce, lane0 writes partials.
        float s[8], q[8];
#pragma unroll
        for (int j = 0; j < 8; ++j) {
            float sj = acc[j][0], qj = acc[j][0] * acc[j][0];
            if (vw) { sj += acc[j][1]; qj = fmaf(acc[j][1], acc[j][1], qj); }
            if (vh) {
                sj += acc[j][2]; qj = fmaf(acc[j][2], acc[j][2], qj);
                if (vw) { sj += acc[j][3]; qj = fmaf(acc[j][3], acc[j][3], qj); }
            }
#pragma unroll
            for (int off = 1; off < 64; off <<= 1) {
                sj += __shfl_xor(sj, off);
                qj += __shfl_xor(qj, off);
            }
            s[j] = sj; q[j] = qj;
        }
        if (lane == 0) {
            const int row = od * 16 + rb;                 // 0..495
            const int base = row * 512 + n * 32 + cob;
#pragma unroll
            for (int j = 0; j < 8; ++j) {
                ws[WS_PS + base + j] = s[j];
                ws[WS_QS + base + j] = q[j];
            }
        }
    } else {
        const int ncb = n * COUT + cob;
        const size_t obase = (((size_t)ncb * DOUT + od) * HOUT + (r << 1)) * WOUT + (c << 1);
#pragma unroll
        for (int j = 0; j < 8; ++j) {
            const float mj  = ws[WS_M + ncb + j];     // uniform -> s_load
            const float scj = ws[WS_SC + cob + j];
            const size_t ob = obase + (size_t)j * S_SPATIAL;
            out[ob] = (acc[j][0] - mj) * scj;
            if (vw) out[ob + 1] = (acc[j][1] - mj) * scj;
            if (vh) {
                out[ob + WOUT] = (acc[j][2] - mj) * scj;
                if (vw) out[ob + WOUT + 1] = (acc[j][3] - mj) * scj;
            }
        }
    }
}

__global__ __launch_bounds__(512) void reduce_kernel(float* __restrict__ ws)
{
    const int t = threadIdx.x;           // nc = n*32+co
    const int r0 = blockIdx.x * 62;      // 8 blocks x 62 rows = 496
    float S = 0.f, Q = 0.f;
    for (int r = r0; r < r0 + 62; ++r) {
        S += ws[WS_PS + r * 512 + t];
        Q += ws[WS_QS + r * 512 + t];
    }
    atomicAdd(&ws[WS_ACCS + t], S);
    atomicAdd(&ws[WS_ACCQ + t], Q);
}

__global__ __launch_bounds__(512) void finalize_kernel(const float* __restrict__ bnw,
                                                       float* __restrict__ ws)
{
    const int t = threadIdx.x;           // 512
    ws[WS_M + t] = ws[WS_ACCS + t] * (1.0f / (float)S_SPATIAL);
    if (t < COUT) {
        float SS = 0.f, QQ = 0.f;
        for (int n2 = 0; n2 < NBATCH; ++n2) {
            SS += ws[WS_ACCS + n2 * 32 + t];
            QQ += ws[WS_ACCQ + n2 * 32 + t];
        }
        const float mean = SS / CNT_ALL;
        const float var  = QQ / CNT_ALL - mean * mean;
        ws[WS_SC + t] = bnw[t] * rsqrtf(var + 1e-5f);
    }
}

extern "C" void kernel_launch(void* const* d_in, const int* in_sizes, int n_in,
                              void* d_out, int out_size, void* d_ws, size_t ws_size,
                              hipStream_t stream)
{
    const float* x   = (const float*)d_in[0];
    const float* w   = (const float*)d_in[1];
    // d_in[2] = conv_bias, d_in[4] = bn_bias: cancel algebraically.
    const float* bnw = (const float*)d_in[3];
    float* out = (float*)d_out;
    float* ws  = (float*)d_ws;

    hipMemsetAsync(ws + WS_ACCS, 0, 1024 * sizeof(float), stream);

    dim3 grid(16, DOUT, NBATCH);   // (rb, od, n)
    conv_pass<0><<<grid, 256, 0, stream>>>(x, w, out, ws);
    reduce_kernel<<<8, 512, 0, stream>>>(ws);
    finalize_kernel<<<1, 512, 0, stream>>>(bnw, ws);
    conv_pass<1><<<grid, 256, 0, stream>>>(x, w, out, ws);
}